// Round 13
// baseline (129.499 us; speedup 1.0000x reference)
//
#include <hip/hip_runtime.h>
#include <hip/hip_bf16.h>

#define B 128
#define N 1024
#define L 512
#define D 64
#define NCH 8                // 128-token chunks per (s,b)

typedef float f32x4 __attribute__((ext_vector_type(4)));
typedef short bf16x8 __attribute__((ext_vector_type(8)));

// 8 fp32 -> 8 bf16 (RNE) via packed HW cvt
__device__ inline bf16x8 cvt8(float4 f0, float4 f1) {
    union { __hip_bfloat162 h2[4]; bf16x8 v; } u;
    u.h2[0] = __float22bfloat162_rn(make_float2(f0.x, f0.y));
    u.h2[1] = __float22bfloat162_rn(make_float2(f0.z, f0.w));
    u.h2[2] = __float22bfloat162_rn(make_float2(f1.x, f1.y));
    u.h2[3] = __float22bfloat162_rn(make_float2(f1.z, f1.w));
    return u.v;
}

// ws layout (bytes):
//   [0)      float partials[3*B*NCH] (3072)
//   [12288)  int   cnts[2*B]
//   [16384)  unsigned short Tbf[B*N*D]  (16.8 MB)  fragment order
//   [16384+16777216) unsigned short Ibf[B*L*D] (8.4 MB) fragment order
#define TBF_OFF 16384
#define IBF_OFF (16384 + 16777216)
#define WS_NEED (IBF_OFF + (size_t)B * L * D * 2)

// Fragment-linear order (identical for T and I): flat 16-row tile t of the
// row-major [rows x 64] fp32 source maps to 2 KB at byte t*2048; within it,
// 16B unit (h, lane) at h*1024 + lane*16 holds row t*16+(lane&15),
// d = h*32 + (lane>>4)*8 .. +8  — exactly one MFMA A/B fragment per lane.
__global__ __launch_bounds__(256) void prep_kernel(
        const float* __restrict__ T, const float* __restrict__ I,
        const float* __restrict__ tmask, const float* __restrict__ imask,
        unsigned short* __restrict__ Tbf, unsigned short* __restrict__ Ibf,
        int* __restrict__ cnts) {
    int blk = blockIdx.x;
    int tid = threadIdx.x;
    __shared__ float red[4];
    if (blk < 3072) {              // swizzle 64 source rows -> 8 KB fragment
        const float* src;
        unsigned short* dst;
        if (blk < 2048) { src = T + (size_t)blk * 64 * D; dst = Tbf + (size_t)blk * 4096; }
        else { src = I + (size_t)(blk - 2048) * 64 * D; dst = Ibf + (size_t)(blk - 2048) * 4096; }
#pragma unroll
        for (int j = 0; j < 2; ++j) {
            int si = tid + j * 256; // 32B source unit: row si>>3, seg si&7
            int r = si >> 3, seg = si & 7;
            const float4* p = (const float4*)(src + (size_t)si * 8);
            bf16x8 v = cvt8(p[0], p[1]);
            int h = seg >> 2, qq = seg & 3;
            int ci = ((r >> 4) * 2 + h) * 64 + qq * 16 + (r & 15);
            *(bf16x8*)(dst + (size_t)ci * 8) = v;
        }
    } else {                       // mask-count rows
        int row = blk - 3072;      // 0..2B-1
        float s = 0.f;
        if (row < B) {
            const float* p = tmask + (size_t)row * N;
            for (int i = tid; i < N; i += 256) s += p[i];
        } else {
            const float* p = imask + (size_t)(row - B) * L;
            for (int i = tid; i < L; i += 256) s += p[i];
        }
        for (int off = 32; off > 0; off >>= 1) s += __shfl_down(s, off);
        if ((tid & 63) == 0) red[tid >> 6] = s;
        __syncthreads();
        if (tid == 0)
            cnts[row] = (int)(red[0] + red[1] + red[2] + red[3] + 0.5f);
    }
}

// grid = 3*B*NCH = 3072 blocks x 256 thr. Block (s,b,128-token chunk).
// Wave w: token-half th=w>>1 (64 tokens = 4 MFMA tiles), REGION-half rh=w&1
// (tiles rt = rh, rh+2, ...). 2x the active waves of R12 (~7.7k, ~6/SIMD)
// and half the per-wave critical path; region-half maxes combine via a 1KB
// LDS table (2 barriers, epilogue only). PRE: zero cvt in sim — A and B both
// load pre-swizzled bf16 fragments (contiguous 16B/lane).
template <bool PRE>
__global__ __launch_bounds__(256, 4) void sim_kernel(
        const float* __restrict__ T, const float* __restrict__ I,
        const unsigned short* __restrict__ Tbf, const unsigned short* __restrict__ Ibf,
        const int* __restrict__ cnts,
        const int* __restrict__ Iimp, const int* __restrict__ Simp,
        float* __restrict__ partials) {
    int blk = blockIdx.x;          // 0..3071
    int chunk = blk & (NCH - 1);
    int bs = blk >> 3;             // 0..383
    int b = bs & (B - 1);
    int s = bs >> 7;
    int Tb = b, Ib = b;
    if (s == 1) Tb = Simp[b];
    else if (s == 2) Ib = Iimp[b];
    int ntok = cnts[Tb];
    int nreg = cnts[B + Ib];

    int tid = threadIdx.x;
    int tok0 = chunk * 128;
    if (tok0 >= ntok) {            // empty chunk: whole block exits pre-barrier
        if (tid == 0) partials[blk] = 0.f;
        return;
    }

    int w = tid >> 6;
    int lane = tid & 63;
    int q = lane >> 4;
    int c = lane & 15;
    int th = w >> 1;               // token half (64 tokens)
    int rh = w & 1;                // region half (tiles rt ≡ rh mod 2)

    __shared__ float ldsmx[2][2][64];   // [token-half][region-half][row]
    __shared__ float wsumS[2];

    int wt0 = tok0 + th * 64;
    bool active = wt0 < ntok;

    float mx[4][4];
#pragma unroll
    for (int tt = 0; tt < 4; ++tt)
#pragma unroll
        for (int i = 0; i < 4; ++i) mx[tt][i] = -3.0e38f;

    int nrt = (nreg + 15) >> 4;
    int prem = nreg & 15;

    if (active) {
        // ---- A fragments: 4 token tiles x 2 K-halves ----
        bf16x8 afrag[4][2];
        if (PRE) {
            const char* tb = (const char*)Tbf + (size_t)Tb * 131072
                           + (size_t)(chunk * 8 + th * 4) * 2048 + (size_t)lane * 16;
#pragma unroll
            for (int tt = 0; tt < 4; ++tt)
#pragma unroll
                for (int h = 0; h < 2; ++h)
                    afrag[tt][h] = *(const bf16x8*)(tb + tt * 2048 + h * 1024);
        } else {
#pragma unroll
            for (int tt = 0; tt < 4; ++tt) {
                const float* trow = T + ((size_t)Tb * N + wt0 + tt * 16 + c) * D;
#pragma unroll
                for (int h = 0; h < 2; ++h) {
                    const float4* p = (const float4*)(trow + h * 32 + q * 8);
                    afrag[tt][h] = cvt8(p[0], p[1]);
                }
            }
        }

        // ---- region tiles rt = rh, rh+2, ... with depth-1 prefetch ----
        if (PRE) {
            const char* imgL = (const char*)Ibf + (size_t)Ib * 65536 + (size_t)lane * 16;
            bf16x8 c0 = {0}, c1 = {0}, n0 = {0}, n1 = {0};
            if (rh < nrt) {
                c0 = *(const bf16x8*)(imgL + (size_t)rh * 2048);
                c1 = *(const bf16x8*)(imgL + (size_t)rh * 2048 + 1024);
            }
#pragma unroll 1
            for (int rt = rh; rt < nrt; rt += 2) {
                int rn = rt + 2;
                if (rn < nrt) {
                    n0 = *(const bf16x8*)(imgL + (size_t)rn * 2048);
                    n1 = *(const bf16x8*)(imgL + (size_t)rn * 2048 + 1024);
                }
                bool vld = (rt != nrt - 1) || (prem == 0) || (c < prem);
#pragma unroll
                for (int tt = 0; tt < 4; ++tt) {
                    f32x4 acc = {0.f, 0.f, 0.f, 0.f};
                    acc = __builtin_amdgcn_mfma_f32_16x16x32_bf16(afrag[tt][0], c0, acc, 0, 0, 0);
                    acc = __builtin_amdgcn_mfma_f32_16x16x32_bf16(afrag[tt][1], c1, acc, 0, 0, 0);
                    if (vld) {
#pragma unroll
                        for (int i = 0; i < 4; ++i) mx[tt][i] = fmaxf(mx[tt][i], acc[i]);
                    }
                }
                c0 = n0; c1 = n1;
            }
        } else {
            const float* Ibase = I + (size_t)Ib * L * D;
#pragma unroll 1
            for (int rt = rh; rt < nrt; rt += 2) {
                int r = rt * 16 + c;                  // <= 511 always
                const float4* p0 = (const float4*)(Ibase + (size_t)r * D + q * 8);
                bf16x8 b0 = cvt8(p0[0], p0[1]);
                const float4* p1 = (const float4*)(Ibase + (size_t)r * D + 32 + q * 8);
                bf16x8 b1 = cvt8(p1[0], p1[1]);
                bool vld = (rt != nrt - 1) || (prem == 0) || (c < prem);
#pragma unroll
                for (int tt = 0; tt < 4; ++tt) {
                    f32x4 acc = {0.f, 0.f, 0.f, 0.f};
                    acc = __builtin_amdgcn_mfma_f32_16x16x32_bf16(afrag[tt][0], b0, acc, 0, 0, 0);
                    acc = __builtin_amdgcn_mfma_f32_16x16x32_bf16(afrag[tt][1], b1, acc, 0, 0, 0);
                    if (vld) {
#pragma unroll
                        for (int i = 0; i < 4; ++i) mx[tt][i] = fmaxf(mx[tt][i], acc[i]);
                    }
                }
            }
        }

        // ---- in-wave max over the 16 region-cols ----
#pragma unroll
        for (int m = 1; m < 16; m <<= 1) {
#pragma unroll
            for (int tt = 0; tt < 4; ++tt)
#pragma unroll
                for (int i = 0; i < 4; ++i)
                    mx[tt][i] = fmaxf(mx[tt][i], __shfl_xor(mx[tt][i], m));
        }
    }

    // ---- publish per-row maxes (row within half = tt*16 + q*4 + i) ----
    if (c == 0) {
#pragma unroll
        for (int tt = 0; tt < 4; ++tt)
#pragma unroll
            for (int i = 0; i < 4; ++i)
                ldsmx[th][rh][tt * 16 + q * 4 + i] = mx[tt][i];
    }
    __syncthreads();

    // ---- combine region halves, masked token sum (one wave per half) ----
    if (rh == 0) {
        float v = fmaxf(ldsmx[th][0][lane], ldsmx[th][1][lane]);
        int row = wt0 + lane;
        float sv = (row < ntok) ? v : 0.f;
        for (int off = 32; off > 0; off >>= 1) sv += __shfl_down(sv, off);
        if (lane == 0) wsumS[th] = sv;
    }
    __syncthreads();
    if (tid == 0)
        partials[blk] = (wsumS[0] + wsumS[1]) / (float)ntok;
}

// 1 block x 384 threads: fold 3072 partials -> 384 sims -> hinge -> loss
__global__ void loss_kernel(const float* __restrict__ partials,
                            float* __restrict__ out) {
    int tid = threadIdx.x;  // 0..383
    __shared__ float simsL[384];
    __shared__ float w6[6];
    float acc = 0.f;
    const float4* p4 = (const float4*)(partials + tid * NCH);
    float4 v0 = p4[0], v1 = p4[1];
    acc = (v0.x + v0.y + v0.z + v0.w) + (v1.x + v1.y + v1.z + v1.w);
    simsL[tid] = acc;
    __syncthreads();
    float per = 0.f;
    if (tid < B) {
        float anc  = simsL[tid];
        float simp = simsL[B + tid];
        float iimp = simsL[2 * B + tid];
        per = fmaxf(1.f + iimp - anc, 0.f) + fmaxf(1.f + simp - anc, 0.f);
    }
    for (int off = 32; off > 0; off >>= 1) per += __shfl_down(per, off);
    if ((tid & 63) == 0) w6[tid >> 6] = per;
    __syncthreads();
    if (tid == 0)
        out[0] = (w6[0] + w6[1] + w6[2] + w6[3] + w6[4] + w6[5]) / (float)B;
}

extern "C" void kernel_launch(void* const* d_in, const int* in_sizes, int n_in,
                              void* d_out, int out_size, void* d_ws, size_t ws_size,
                              hipStream_t stream) {
    const float* T     = (const float*)d_in[0];
    const float* I     = (const float*)d_in[1];
    const float* tmask = (const float*)d_in[2];
    const float* imask = (const float*)d_in[3];
    const int*   Iimp  = (const int*)d_in[4];
    const int*   Simp  = (const int*)d_in[5];

    float* partials = (float*)d_ws;                          // 3072 f
    int*   cnts     = (int*)((char*)d_ws + 12288);           // 256 i
    unsigned short* Tbf = (unsigned short*)((char*)d_ws + TBF_OFF);
    unsigned short* Ibf = (unsigned short*)((char*)d_ws + IBF_OFF);

    prep_kernel<<<3072 + 2 * B, 256, 0, stream>>>(T, I, tmask, imask, Tbf, Ibf, cnts);
    if (ws_size >= WS_NEED) {
        sim_kernel<true><<<3 * B * NCH, 256, 0, stream>>>(T, I, Tbf, Ibf, cnts,
                                                          Iimp, Simp, partials);
    } else {
        sim_kernel<false><<<3 * B * NCH, 256, 0, stream>>>(T, I, Tbf, Ibf, cnts,
                                                           Iimp, Simp, partials);
    }
    loss_kernel<<<1, 384, 0, stream>>>(partials, (float*)d_out);
}